// Round 1
// 780.456 us; speedup vs baseline: 2.2324x; 2.2324x over previous
//
#include <hip/hip_runtime.h>
#include <cstdint>
#include <cstddef>

#define B_ 8
#define C_ 512
#define T_ 8192

typedef unsigned short ushort_t;
typedef __attribute__((ext_vector_type(8))) short short8;            // 8 bf16 = 4 VGPR (MFMA A/B frag)
typedef __attribute__((ext_vector_type(8))) unsigned short ushort8_t;
typedef __attribute__((ext_vector_type(4))) float floatx4;           // MFMA C/D frag
typedef __attribute__((ext_vector_type(4))) unsigned int uintx4;

__device__ __forceinline__ ushort_t f2bf(float f) {
    // round-to-nearest-even fp32 -> bf16 (finite inputs)
    unsigned int u = __float_as_uint(f);
    u += 0x7FFFu + ((u >> 16) & 1u);
    return (ushort_t)(u >> 16);
}

// ---------------------------------------------------------------------------
// Fused Activation1d producing TRANSPOSED bf16 output z_T[b][t][c].
// Closed form (verified):
//   y[2u]   = 2*sum_q x_c[u-3+q]*f[11-2q]
//   y[2u+1] = 2*sum_q x_c[u-2+q]*f[10-2q]
//   s(y)    = y + invb*sin(y*alpha)^2
//   z[t]    = sum_j g[j]*s(y[clamp(2t-5+j, 0, 2T-1)])   (x-index replicate-clamped)
//
// v2 structure: block = 32c x 128t tile, 256 threads.
//  1) coalesced float4 staging of x[c0..c0+31][t0-8 .. t0+135] into LDS
//     (x replicate-pad clamping folded into staging)
//  2) thread (cl = tid&31, st = tid>>5) computes c = c0+cl, t = t0+st*16..+15.
//     Loads its 32-float window from LDS to regs (8x ds_read_b128), streams the
//     42 shared y-values (each: 6 FMA + sin + snake), scatter-accumulating into
//     16 z registers.  Per-output cost ~40 lane-ops vs ~150 in v1.
//  3) transpose via LDS (stride 40 halves: write 2-way-free, read 16B aligned),
//     coalesced 16B global stores of z_T tile.
// Edge t-blocks (2 of 64) take a scalar clamped path (y-index clamp there).
// ---------------------------------------------------------------------------
#define CT   32     // channels per block
#define TT   128    // t per block
#define XSTR 148    // LDS x row stride (floats): 592B, 16B-aligned, not bank-aligned
#define ZSTR 40     // z stage row stride (halves): 80B, 16B-aligned

__global__ __launch_bounds__(256) void act_t_kernel(
    const float* __restrict__ X,   // [B][C][T] fp32
    const float* __restrict__ la, const float* __restrict__ lb,
    const float* __restrict__ fu, const float* __restrict__ fd,
    ushort_t* __restrict__ Zt)     // [B][T][C] bf16
{
    __shared__ __align__(16) float    xl[CT * XSTR];   // 18944 B
    __shared__ __align__(16) ushort_t zs[TT * ZSTR];   // 10240 B

    const int t0  = blockIdx.x * TT;
    const int c0  = blockIdx.y * CT;
    const int b   = blockIdx.z;
    const int tid = threadIdx.x;

    const bool interior = (t0 >= 8) && (t0 + 136 <= T_);

    // ---- stage x rows [c0..c0+31] x global t in [t0-8, t0+136) ----
    {
        const int row = tid >> 3;          // 0..31
        const int js  = tid & 7;           // 8 threads per row
        const float* Xr = X + ((size_t)b * C_ + c0 + row) * T_;
        if (interior) {
            const float* src = Xr + (t0 - 8);   // 16B-aligned (t0 % 128 == 0)
#pragma unroll
            for (int k = 0; k < 5; ++k) {
                const int seg = js + k * 8;
                if (seg < 36)
                    *(floatx4*)&xl[row * XSTR + seg * 4] = *(const floatx4*)&src[seg * 4];
            }
        } else {
            // replicate-pad clamp folded into staging
#pragma unroll
            for (int e = 0; e < 18; ++e) {
                const int i = js * 18 + e;
                int t = t0 - 8 + i;
                t = min(max(t, 0), T_ - 1);
                xl[row * XSTR + i] = Xr[t];
            }
        }
    }

    float f[12], g[12];
#pragma unroll
    for (int j = 0; j < 12; ++j) { f[j] = fu[j]; g[j] = fd[j]; }

    const int cl   = tid & 31;
    const int st   = tid >> 5;       // 0..7
    const int st16 = st * 16;
    const int c    = c0 + cl;
    const float alpha = __expf(la[c]);
    const float invb  = 1.0f / (__expf(lb[c]) + 1e-9f);

    __syncthreads();

    float zacc[16];
#pragma unroll
    for (int i = 0; i < 16; ++i) zacc[i] = 0.f;

    // y-stream index m = 0..41 maps to n = 2*(t0+st16) - 5 + m.
    //   m even -> n odd:  y = 2*sum_q x[ts-5+h+q]*f[10-2q]   (h = m>>1)
    //   m odd  -> n even: y = 2*sum_q x[ts-5+h+q]*f[11-2q]
    // z[dt] += g[m-2dt]*s(y) for dt in [ceil((m-11)/2), floor(m/2)] cap [0,15].
    if (interior) {
        float xw[32];     // xw[i] = x[t0 + st16 - 8 + i]; window use: xw[3+h+q]
#pragma unroll
        for (int i = 0; i < 8; ++i)
            *(floatx4*)&xw[i * 4] = *(const floatx4*)&xl[cl * XSTR + st16 + i * 4];

#pragma unroll
        for (int m = 0; m < 42; ++m) {
            const int h = m >> 1;
            float y = 0.f;
            if (m & 1) {
#pragma unroll
                for (int q = 0; q < 6; ++q) y += xw[3 + h + q] * f[11 - 2 * q];
            } else {
#pragma unroll
                for (int q = 0; q < 6; ++q) y += xw[3 + h + q] * f[10 - 2 * q];
            }
            y *= 2.f;
            const float sn = __sinf(y * alpha);
            y += invb * sn * sn;
            const int dlo = (m >= 11) ? ((m - 10) >> 1) : 0;
            const int dhi = (h < 15) ? h : 15;
#pragma unroll
            for (int dt = dlo; dt <= dhi; ++dt)
                zacc[dt] += g[m - 2 * dt] * y;
        }
    } else {
        // edge: y-index clamp active; read x scalars from LDS (already x-clamped)
        const int ts = t0 + st16;
        const float* xr = &xl[cl * XSTR];
#pragma unroll
        for (int m = 0; m < 42; ++m) {
            const int h = m >> 1;
            int n = 2 * ts - 5 + m;
            n = min(max(n, 0), 2 * T_ - 1);
            const int u    = n >> 1;
            const int base = u - (t0 - 8);   // LDS-local index of x[u]
            float y = 0.f;
            if (n & 1) {
#pragma unroll
                for (int q = 0; q < 6; ++q) y += xr[base - 2 + q] * f[10 - 2 * q];
            } else {
#pragma unroll
                for (int q = 0; q < 6; ++q) y += xr[base - 3 + q] * f[11 - 2 * q];
            }
            y *= 2.f;
            const float sn = __sinf(y * alpha);
            y += invb * sn * sn;
            const int dlo = (m >= 11) ? ((m - 10) >> 1) : 0;
            const int dhi = (h < 15) ? h : 15;
#pragma unroll
            for (int dt = dlo; dt <= dhi; ++dt)
                zacc[dt] += g[m - 2 * dt] * y;
        }
    }

    // transpose-stage z: row = local t, col = cl.  2 groups of 32 consecutive
    // halves per wave row-write -> 2 words/bank = free.
#pragma unroll
    for (int r = 0; r < 16; ++r)
        zs[(st16 + r) * ZSTR + cl] = f2bf(zacc[r]);

    __syncthreads();

    // coalesced write-out: 128 rows x 64B; (row, seg) per thread x2
    const int seg = tid & 3;
    const int rr  = tid >> 2;     // 0..63
#pragma unroll
    for (int p = 0; p < 2; ++p) {
        const int row = p * 64 + rr;
        *(uintx4*)&Zt[((size_t)b * T_ + t0 + row) * C_ + c0 + seg * 8] =
            *(const uintx4*)&zs[row * ZSTR + seg * 8];
    }
}

// ---------------------------------------------------------------------------
// Pack W [o][c][k] fp32 -> MFMA-fragment-ordered bf16:
// Wb[(k*16+chunk)*32 + ot][lane][j] = W[ot*16+(lane&15)][chunk*32+(lane>>4)*8+j][k]
// One thread per 16B output segment. 98304 threads.
// ---------------------------------------------------------------------------
__global__ __launch_bounds__(256) void pack_w_kernel(
    const float* __restrict__ W, ushort_t* __restrict__ Wb)
{
    const int gid   = blockIdx.x * 256 + threadIdx.x;   // 0..98303
    const int lane  = gid & 63;
    const int rest  = gid >> 6;          // k*512 + chunk*32 + ot
    const int ot    = rest & 31;
    const int chunk = (rest >> 5) & 15;
    const int k     = rest >> 9;
    const int o     = ot * 16 + (lane & 15);
    const int c0    = chunk * 32 + (lane >> 4) * 8;
    ushort8_t v;
#pragma unroll
    for (int j = 0; j < 8; ++j)
        v[j] = f2bf(W[((size_t)o * C_ + c0 + j) * 3 + k]);
    *(ushort8_t*)&Wb[(size_t)gid * 8] = v;
}

// ---------------------------------------------------------------------------
// Conv1d C->C K=3 zero-pad as 3 shifted bf16 MFMA GEMMs, fp32 accumulate.
// O[o][t] = bias[o] + sum_k sum_c W[o][c][k] * z_T[t+k-1][c]   (+ resid)
// Block tile 128(o) x 128(t); 4 waves each 64x64 via 16x16x32_bf16.
// A staged with global_load_lds (frag-ordered Wb), B staged 130 rows x 32c.
// ---------------------------------------------------------------------------
__global__ __launch_bounds__(256) void conv_mfma_kernel(
    const ushort_t* __restrict__ Zt,   // [B][T][C] bf16
    const ushort_t* __restrict__ Wb,   // frag-packed weights
    const float* __restrict__ bias,
    const float* __restrict__ resid,
    float* __restrict__ Out,           // [B][C][T] fp32
    const int addResid)
{
    __shared__ __align__(16) ushort_t Al[3 * 8 * 512];   // 24KB: [k][ot][lane*8]
    __shared__ __align__(16) ushort_t Bl[130 * 40];      // 10.4KB: rows t0-1.., stride 40 halves

    const int t0  = blockIdx.x * 128;
    const int o0  = blockIdx.y * 128;
    const int b   = blockIdx.z;
    const int tid = threadIdx.x;
    const int lane = tid & 63;
    const int w    = tid >> 6;
    const int wo   = w & 1;        // o half
    const int wt   = w >> 1;       // t half

    const ushort_t* zb = Zt + (size_t)b * T_ * C_;

    floatx4 acc[4][4];
#pragma unroll
    for (int i = 0; i < 4; ++i)
#pragma unroll
        for (int j = 0; j < 4; ++j)
            acc[i][j] = (floatx4){0.f, 0.f, 0.f, 0.f};

    const int rB = tid >> 2;   // 0..63
    const int qB = tid & 3;

    for (int chunk = 0; chunk < 16; ++chunk) {
        const int c0 = chunk * 32;

        // --- A: async global->LDS, 24 segments of 1KB; wave w owns segs w*6..w*6+5
#pragma unroll
        for (int s = 0; s < 6; ++s) {
            const int seg = w * 6 + s;
            const int k   = seg >> 3;
            const int ot8 = seg & 7;
            const ushort_t* gsrc =
                Wb + (size_t)(((k * 16 + chunk) * 32) + (o0 >> 4) + ot8) * 512 + lane * 8;
            __builtin_amdgcn_global_load_lds(
                (const __attribute__((address_space(1))) unsigned int*)gsrc,
                (__attribute__((address_space(3))) unsigned int*)&Al[seg * 512],
                16, 0, 0);
        }

        // --- B: 130 rows (t0-1 .. t0+128) x 32 c, zero-padded at t edges
#pragma unroll
        for (int p = 0; p < 3; ++p) {
            const int r = rB + p * 64;
            if (r < 130) {
                const int t = t0 - 1 + r;
                uintx4 v = (uintx4){0u, 0u, 0u, 0u};
                if (t >= 0 && t < T_)
                    v = *(const uintx4*)&zb[(size_t)t * C_ + c0 + qB * 8];
                *(uintx4*)&Bl[r * 40 + qB * 8] = v;
            }
        }
        __syncthreads();

#pragma unroll
        for (int k = 0; k < 3; ++k) {
            short8 af[4], bf[4];
#pragma unroll
            for (int i = 0; i < 4; ++i)
                af[i] = *(const short8*)&Al[(k * 8 + wo * 4 + i) * 512 + lane * 8];
#pragma unroll
            for (int j = 0; j < 4; ++j)
                bf[j] = *(const short8*)&Bl[(wt * 64 + j * 16 + (lane & 15) + k) * 40 + (lane >> 4) * 8];
#pragma unroll
            for (int i = 0; i < 4; ++i)
#pragma unroll
                for (int j = 0; j < 4; ++j)
                    acc[i][j] = __builtin_amdgcn_mfma_f32_16x16x32_bf16(af[i], bf[j], acc[i][j], 0, 0, 0);
        }
        __syncthreads();
    }

    // --- epilogue: D[row=o][col=t], row=(lane>>4)*4+reg, col=lane&15
    const int tc0 = t0 + wt * 64 + (lane & 15);
#pragma unroll
    for (int i = 0; i < 4; ++i) {
        const int ob = o0 + wo * 64 + i * 16 + (lane >> 4) * 4;
#pragma unroll
        for (int r = 0; r < 4; ++r) {
            const int o = ob + r;
            const float bs = bias[o];
            const size_t rowoff = ((size_t)b * C_ + o) * T_;
#pragma unroll
            for (int j = 0; j < 4; ++j) {
                const int t = tc0 + j * 16;
                float v = acc[i][j][r] + bs;
                if (addResid) v += resid[rowoff + t];
                Out[rowoff + t] = v;
            }
        }
    }
}

extern "C" void kernel_launch(void* const* d_in, const int* in_sizes, int n_in,
                              void* d_out, int out_size, void* d_ws, size_t ws_size,
                              hipStream_t stream)
{
    const float* x   = (const float*)d_in[0];
    const float* a1a = (const float*)d_in[1];
    const float* a1b = (const float*)d_in[2];
    const float* a2a = (const float*)d_in[3];
    const float* a2b = (const float*)d_in[4];
    const float* c1w = (const float*)d_in[5];
    const float* c1b = (const float*)d_in[6];
    const float* c2w = (const float*)d_in[7];
    const float* c2b = (const float*)d_in[8];
    const float* fu  = (const float*)d_in[9];
    const float* fd  = (const float*)d_in[10];
    float* out = (float*)d_out;

    // workspace layout
    ushort_t* Zt  = (ushort_t*)d_ws;                                   // 67,108,864 B
    float*    y1  = (float*)((char*)d_ws + 67108864);                  // 134,217,728 B
    ushort_t* Wb1 = (ushort_t*)((char*)d_ws + 67108864 + 134217728);   // 1,572,864 B
    ushort_t* Wb2 = Wb1 + 786432;                                      // 1,572,864 B

    dim3 agrid(T_ / TT, C_ / CT, B_);
    dim3 cgrid(T_ / 128, C_ / 128, B_);

    pack_w_kernel<<<384, 256, 0, stream>>>(c1w, Wb1);
    pack_w_kernel<<<384, 256, 0, stream>>>(c2w, Wb2);

    // xt = act1(x) -> z_T bf16
    act_t_kernel<<<agrid, 256, 0, stream>>>(x, a1a, a1b, fu, fd, Zt);
    // xt = conv1(xt) -> y1 fp32
    conv_mfma_kernel<<<cgrid, 256, 0, stream>>>(Zt, Wb1, c1b, x, y1, 0);
    // xt = act2(xt) -> z_T bf16
    act_t_kernel<<<agrid, 256, 0, stream>>>(y1, a2a, a2b, fu, fd, Zt);
    // out = conv2(xt) + x
    conv_mfma_kernel<<<cgrid, 256, 0, stream>>>(Zt, Wb2, c2b, x, out, 1);
}